// Round 5
// baseline (340.720 us; speedup 1.0000x reference)
//
#include <hip/hip_runtime.h>
#include <hip/hip_bf16.h>
#include <hip/hip_fp16.h>

typedef __bf16 bf16x8 __attribute__((ext_vector_type(8)));
typedef float  f32x4  __attribute__((ext_vector_type(4)));

#define C_H 56
#define C_W 56
#define C_C 256
#define C_F 256
#define C_B 64
#define N_PIX (C_B * C_H * C_W)          // 200704
#define WB_ELEMS (9 * C_C * C_F)         // 589824
#define WB_BYTES (WB_ELEMS * 2)          // 1179648
#define ZBUF_BYTES 1024
#define XB_OFF (WB_BYTES + ZBUF_BYTES)   // 1180672 (16B aligned)
#define X_ELEMS (N_PIX * C_C)            // 51380224

#define GLOAD_LDS16(g, l)                                                   \
    __builtin_amdgcn_global_load_lds(                                        \
        (const __attribute__((address_space(1))) void*)(g),                  \
        (__attribute__((address_space(3))) void*)(l), 16, 0, 0)

// ---- prep: binarize + transpose weights: w[s][c][f] fp32 -> wbT[s][f][c] bf16 ----
__global__ void prep_w_kernel(const float* __restrict__ w, __bf16* __restrict__ wbT) {
    int idx = blockIdx.x * 256 + threadIdx.x;       // 589824 total
    int f = idx & 255;
    int c = (idx >> 8) & 255;
    int s = idx >> 16;
    float wf = w[idx];
    float v = __half2float(__float2half(wf));       // fp16 round-trip
    float sgn = (v > 0.f) ? 1.f : ((v < 0.f) ? -1.f : 0.f);
    wbT[(s << 16) + (f << 8) + c] = (__bf16)sgn;
}

__global__ void zero_kernel(float* __restrict__ z) {
    z[threadIdx.x] = 0.f;   // 1KB zero page
}

__global__ void prep_x_kernel(const float* __restrict__ x, __bf16* __restrict__ xb) {
    int i = blockIdx.x * 256 + threadIdx.x;
    const f32x4* p = reinterpret_cast<const f32x4*>(x) + (size_t)i * 2;
    f32x4 a = p[0], b = p[1];
    bf16x8 o;
    o[0] = (__bf16)a[0]; o[1] = (__bf16)a[1]; o[2] = (__bf16)a[2]; o[3] = (__bf16)a[3];
    o[4] = (__bf16)b[0]; o[5] = (__bf16)b[1]; o[6] = (__bf16)b[2]; o[7] = (__bf16)b[3];
    reinterpret_cast<bf16x8*>(xb)[i] = o;
}

// ---- main conv: 256x256 tile, 8 waves (2Mx4N, 128x64/wave), BK=32 ----
// m201-style 8-phase schedule: 2 phases per K-step, counted vmcnt(8), 4 LDS bufs.
// Phase = {ds_read frags | stage half of step kt+3 -> buf[(q+3)&3]} barrier
//          lgkmcnt(0); 16 MFMA; [vmcnt(8) if h==1]; barrier.
__global__ __launch_bounds__(512, 2) void conv_mfma8_kernel(
    const char* __restrict__ xbp,      // bf16 x [pixel][256c], 512B rows
    const char* __restrict__ wbp,      // bf16 wbT[s][f][c], 512B rows
    const char* __restrict__ zp,       // >=128B zeros, 16B aligned
    float* __restrict__ out) {

    __shared__ __align__(16) char sm[4][32768];   // [buf][A 16KB | B 16KB]

    // XCD-aware chunked swizzle: 784 blocks = 8 XCDs x 98
    const int nbid = (blockIdx.x & 7) * 98 + (blockIdx.x >> 3);
    const long m0 = (long)nbid * 256;

    const int tid  = threadIdx.x;
    const int lane = tid & 63;
    const int wave = tid >> 6;          // 0..7
    const int l15  = lane & 15;
    const int g4   = lane >> 4;         // 0..3
    const int wm   = wave >> 2;         // 0..1  (M half)
    const int wn   = wave & 3;          // 0..3  (N quarter)
    const int colr = ((g4 ^ ((l15 >> 1) & 3)) << 4);        // swizzled read chunk
    const int rdA = (wm * 128 + l15) * 64 + colr;           // A frag base (+ai*1024)
    const int rdB = 16384 + (wn * 64 + l15) * 64 + colr;    // B frag base (+bj*1024)

    // ---- staging precompute: thread covers rows r0, r0+128, chunk tid&3 ----
    const int r0 = tid >> 2;                             // 0..127
    const int sw = ((tid & 3) ^ ((r0 >> 1) & 3)) << 4;   // inverse-swizzled source col
    const int p0 = (int)m0 + r0;
    const int p1 = p0 + 128;
    const int rem0 = p0 % 3136;
    const int rem1 = p1 % 3136;
    const int y0 = rem0 / 56, x0 = rem0 - (rem0 / 56) * 56;
    const int y1 = rem1 / 56, x1 = rem1 - (rem1 / 56) * 56;

    // stage half a K-step: abHalf 0 = A (2 loads), 1 = B (2 loads)
    auto stage_half = [&](int kt, int abHalf) {
        int cc = (kt * 57) >> 9;             // kt/9 for kt<81
        int s  = kt - 9 * cc;
        char* L = &sm[kt & 3][0];
        size_t cb = (size_t)(cc << 6) + sw;
        if (abHalf == 0) {
            int s3 = (s * 171) >> 9;         // s/3
            int dy = s3 - 1;
            int dx = s - 3 * s3 - 1;
            int doff = dy * 56 + dx;
            bool v0 = ((unsigned)(y0 + dy) < 56u) & ((unsigned)(x0 + dx) < 56u);
            bool v1 = ((unsigned)(y1 + dy) < 56u) & ((unsigned)(x1 + dx) < 56u);
            const char* a0 = v0 ? xbp + (size_t)(p0 + doff) * 512 + cb : zp + sw;
            const char* a1 = v1 ? xbp + (size_t)(p1 + doff) * 512 + cb : zp + sw;
            GLOAD_LDS16(a0, L + tid * 16);
            GLOAD_LDS16(a1, L + 8192 + tid * 16);
        } else {
            const char* b0 = wbp + (size_t)((s << 8) + r0) * 512 + cb;
            const char* b1 = wbp + (size_t)((s << 8) + r0 + 128) * 512 + cb;
            GLOAD_LDS16(b0, L + 16384 + tid * 16);
            GLOAD_LDS16(b1, L + 24576 + tid * 16);
        }
    };

    f32x4 acc[8][4];
#pragma unroll
    for (int i = 0; i < 8; ++i)
#pragma unroll
        for (int j = 0; j < 4; ++j)
            acc[i][j] = (f32x4){0.f, 0.f, 0.f, 0.f};

    bf16x8 Af[4], Bf[4];

#define VM8 asm volatile("s_waitcnt vmcnt(8)" ::: "memory")
#define VM4 asm volatile("s_waitcnt vmcnt(4)" ::: "memory")
#define VM0 asm volatile("s_waitcnt vmcnt(0)" ::: "memory")

#define PHASE(Q, H, DOSTAGE, TAILWAIT)                                      \
    {                                                                        \
        const char* Lb = &sm[(Q)][0];                                        \
        if ((H) == 0) {                                                      \
            _Pragma("unroll")                                                \
            for (int bj = 0; bj < 4; ++bj)                                   \
                Bf[bj] = *reinterpret_cast<const bf16x8*>(Lb + rdB + bj * 1024); \
        }                                                                    \
        _Pragma("unroll")                                                    \
        for (int ai = 0; ai < 4; ++ai)                                       \
            Af[ai] = *reinterpret_cast<const bf16x8*>(Lb + rdA + ((H) * 4 + ai) * 1024); \
        if (DOSTAGE) stage_half(kt + 3, (H));                                \
        __builtin_amdgcn_s_barrier();                                        \
        asm volatile("s_waitcnt lgkmcnt(0)" ::: "memory");                   \
        __builtin_amdgcn_sched_barrier(0);                                   \
        __builtin_amdgcn_s_setprio(1);                                       \
        _Pragma("unroll")                                                    \
        for (int ai = 0; ai < 4; ++ai)                                       \
            _Pragma("unroll")                                                \
            for (int bj = 0; bj < 4; ++bj)                                   \
                acc[(H) * 4 + ai][bj] = __builtin_amdgcn_mfma_f32_16x16x32_bf16( \
                    Af[ai], Bf[bj], acc[(H) * 4 + ai][bj], 0, 0, 0);         \
        __builtin_amdgcn_s_setprio(0);                                       \
        __builtin_amdgcn_sched_barrier(0);                                   \
        TAILWAIT;                                                            \
        __builtin_amdgcn_s_barrier();                                        \
    }

    // ---- prologue: stage steps 0,1,2 (12 loads); wait step0; barrier ----
    stage_half(0, 0); stage_half(0, 1);
    stage_half(1, 0); stage_half(1, 1);
    stage_half(2, 0); stage_half(2, 1);
    VM8;
    __builtin_amdgcn_s_barrier();

    // ---- main loop: it 0..16, kt 0..67, uniform vmcnt(8) ----
    for (int it = 0; it < 17; ++it) {
        int kt;
        kt = it * 4 + 0; PHASE(0, 0, true, ); PHASE(0, 1, true, VM8);
        kt = it * 4 + 1; PHASE(1, 0, true, ); PHASE(1, 1, true, VM8);
        kt = it * 4 + 2; PHASE(2, 0, true, ); PHASE(2, 1, true, VM8);
        kt = it * 4 + 3; PHASE(3, 0, true, ); PHASE(3, 1, true, VM8);
    }
    // ---- peeled tail: kt 68..71 ----
    { int kt = 68; PHASE(0, 0, true,  ); PHASE(0, 1, true,  VM8); }  // stages 71
    { int kt = 69; PHASE(1, 0, false, ); PHASE(1, 1, false, VM4); }
    { int kt = 70; PHASE(2, 0, false, ); PHASE(2, 1, false, VM0); }
    { int kt = 71; PHASE(3, 0, false, ); PHASE(3, 1, false, ); }

#undef PHASE

    // ---- epilogue: D col(f)=lane&15, row(pixel)=(lane>>4)*4+j ----
#pragma unroll
    for (int ai = 0; ai < 8; ++ai) {
#pragma unroll
        for (int j = 0; j < 4; ++j) {
            long row = m0 + wm * 128 + ai * 16 + g4 * 4 + j;
            float* op = out + row * C_F + wn * 64 + l15;
#pragma unroll
            for (int bj = 0; bj < 4; ++bj)
                op[bj * 16] = acc[ai][bj][j];
        }
    }
}

// ---- fallback (small ws): direct-from-global version ----
__global__ __launch_bounds__(256) void conv_fallback_kernel(
    const float* __restrict__ xf,
    const __bf16* __restrict__ wbT, const char* __restrict__ zbuf,
    float* __restrict__ out) {

    const int lane = threadIdx.x & 63;
    const int wave = threadIdx.x >> 6;
    const int l15  = lane & 15;
    const int g    = lane >> 4;
    const int goff = g * 8;
    const long m0  = (long)blockIdx.x * 64;
    const int fbase = wave * 64;

    int ry[4], rx[4];
    long rbase[4];
#pragma unroll
    for (int ai = 0; ai < 4; ++ai) {
        int rr = (int)m0 + ai * 16 + l15;
        int b = rr / 3136;
        int rem = rr - b * 3136;
        int yy2 = rem / 56;
        ry[ai] = yy2;
        rx[ai] = rem - yy2 * 56;
        rbase[ai] = (long)rr * C_C;
    }

    f32x4 acc[4][4];
#pragma unroll
    for (int i = 0; i < 4; ++i)
#pragma unroll
        for (int j = 0; j < 4; ++j)
            acc[i][j] = (f32x4){0.f, 0.f, 0.f, 0.f};

    for (int s = 0; s < 9; ++s) {
        const int dy = s / 3 - 1;
        const int dx = (s - (s / 3) * 3) - 1;
        const float* af[4];
#pragma unroll
        for (int ai = 0; ai < 4; ++ai) {
            bool v = ((unsigned)(ry[ai] + dy) < 56u) & ((unsigned)(rx[ai] + dx) < 56u);
            long off = rbase[ai] + (long)(dy * C_W + dx) * C_C + goff;
            af[ai] = v ? (xf + off) : ((const float*)zbuf + goff);
        }
        const __bf16* bp = wbT + ((size_t)(s * 256 + fbase + l15)) * C_C + goff;

#pragma unroll
        for (int cc = 0; cc < 8; ++cc) {
            const int c0 = cc * 32;
            bf16x8 A[4], Bf[4];
#pragma unroll
            for (int ai = 0; ai < 4; ++ai) {
                const f32x4* p = reinterpret_cast<const f32x4*>(af[ai] + c0);
                f32x4 u = p[0], w2 = p[1];
                bf16x8 t;
                t[0] = (__bf16)u[0]; t[1] = (__bf16)u[1]; t[2] = (__bf16)u[2]; t[3] = (__bf16)u[3];
                t[4] = (__bf16)w2[0]; t[5] = (__bf16)w2[1]; t[6] = (__bf16)w2[2]; t[7] = (__bf16)w2[3];
                A[ai] = t;
            }
#pragma unroll
            for (int bj = 0; bj < 4; ++bj)
                Bf[bj] = *reinterpret_cast<const bf16x8*>(bp + bj * 16 * C_C + c0);
#pragma unroll
            for (int ai = 0; ai < 4; ++ai)
#pragma unroll
                for (int bj = 0; bj < 4; ++bj)
                    acc[ai][bj] = __builtin_amdgcn_mfma_f32_16x16x32_bf16(A[ai], Bf[bj], acc[ai][bj], 0, 0, 0);
        }
    }

#pragma unroll
    for (int ai = 0; ai < 4; ++ai) {
#pragma unroll
        for (int j = 0; j < 4; ++j) {
            long row = m0 + ai * 16 + g * 4 + j;
            float* op = out + row * C_F + fbase + l15;
#pragma unroll
            for (int bj = 0; bj < 4; ++bj)
                op[bj * 16] = acc[ai][bj][j];
        }
    }
}

extern "C" void kernel_launch(void* const* d_in, const int* in_sizes, int n_in,
                              void* d_out, int out_size, void* d_ws, size_t ws_size,
                              hipStream_t stream) {
    const float* x = (const float*)d_in[0];
    const float* w = (const float*)d_in[1];
    float* out = (float*)d_out;

    char* ws = (char*)d_ws;
    __bf16* wbT = (__bf16*)ws;
    char* zbuf = ws + WB_BYTES;
    __bf16* xb = (__bf16*)(ws + XB_OFF);

    const bool prex = ws_size >= (size_t)XB_OFF + (size_t)X_ELEMS * 2;

    prep_w_kernel<<<WB_ELEMS / 256, 256, 0, stream>>>(w, wbT);
    zero_kernel<<<1, 256, 0, stream>>>((float*)zbuf);

    if (prex) {
        prep_x_kernel<<<X_ELEMS / 8 / 256, 256, 0, stream>>>(x, xb);
        conv_mfma8_kernel<<<N_PIX / 256, 512, 0, stream>>>(
            (const char*)xb, (const char*)wbT, zbuf, out);
    } else {
        conv_fallback_kernel<<<N_PIX / 64, 256, 0, stream>>>(x, wbT, zbuf, out);
    }
}

// Round 6
// 316.934 us; speedup vs baseline: 1.0750x; 1.0750x over previous
//
#include <hip/hip_runtime.h>
#include <hip/hip_bf16.h>
#include <hip/hip_fp16.h>

typedef __bf16 bf16x8 __attribute__((ext_vector_type(8)));
typedef float  f32x4  __attribute__((ext_vector_type(4)));

#define C_H 56
#define C_W 56
#define C_C 256
#define C_F 256
#define C_B 64
#define N_PIX (C_B * C_H * C_W)          // 200704
#define WB_ELEMS (9 * C_C * C_F)         // 589824
#define WB_BYTES (WB_ELEMS * 2)          // 1179648
#define ZBUF_BYTES 1024
#define XB_OFF (WB_BYTES + ZBUF_BYTES)   // 1180672 (16B aligned)
#define X_ELEMS (N_PIX * C_C)            // 51380224

#define GLOAD_LDS16(g, l)                                                   \
    __builtin_amdgcn_global_load_lds(                                        \
        (const __attribute__((address_space(1))) void*)(g),                  \
        (__attribute__((address_space(3))) void*)(l), 16, 0, 0)

// ---- prep: binarize + transpose weights: w[s][c][f] fp32 -> wbT[s][f][c] bf16 ----
__global__ void prep_w_kernel(const float* __restrict__ w, __bf16* __restrict__ wbT) {
    int idx = blockIdx.x * 256 + threadIdx.x;       // 589824 total
    int f = idx & 255;
    int c = (idx >> 8) & 255;
    int s = idx >> 16;
    float wf = w[idx];
    float v = __half2float(__float2half(wf));       // fp16 round-trip
    float sgn = (v > 0.f) ? 1.f : ((v < 0.f) ? -1.f : 0.f);
    wbT[(s << 16) + (f << 8) + c] = (__bf16)sgn;
}

__global__ void zero_kernel(float* __restrict__ z) {
    z[threadIdx.x] = 0.f;   // 1KB zero page
}

__global__ void prep_x_kernel(const float* __restrict__ x, __bf16* __restrict__ xb) {
    int i = blockIdx.x * 256 + threadIdx.x;
    const f32x4* p = reinterpret_cast<const f32x4*>(x) + (size_t)i * 2;
    f32x4 a = p[0], b = p[1];
    bf16x8 o;
    o[0] = (__bf16)a[0]; o[1] = (__bf16)a[1]; o[2] = (__bf16)a[2]; o[3] = (__bf16)a[3];
    o[4] = (__bf16)b[0]; o[5] = (__bf16)b[1]; o[6] = (__bf16)b[2]; o[7] = (__bf16)b[3];
    reinterpret_cast<bf16x8*>(xb)[i] = o;
}

// ---- main conv: 128x128 tile, 4 waves (2Mx2N, 64x64/wave), BK=32, 72 K-steps ----
// cc-major K (s fastest -> x reads L2-hot). 3 LDS bufs x 16KB; lookahead +2;
// counted vmcnt(4); ONE raw barrier per K-step; no drain until tail.
// ~3 blocks/CU for cross-block TLP (the R2 regime) + no per-step vmcnt(0) stall.
// Swizzle (64B rows): chunk' = chunk ^ ((row>>1)&3), applied source + read.
__global__ __launch_bounds__(256, 3) void conv_p3_kernel(
    const char* __restrict__ xbp,      // bf16 x [pixel][256c], 512B rows
    const char* __restrict__ wbp,      // bf16 wbT[s][f][c], 512B rows
    const char* __restrict__ zp,       // >=128B zeros, 16B aligned
    float* __restrict__ out) {

    __shared__ __align__(16) char sm[3][16384];   // [buf][A 8KB | B 8KB]

    // XCD-aware chunked swizzle: 3136 blocks = 8 XCDs x 392
    const int nbid = (blockIdx.x & 7) * 392 + (blockIdx.x >> 3);
    const int mtile = nbid >> 1;
    const int ftile = nbid & 1;            // A-sharing pair adjacent on one XCD
    const long m0 = (long)mtile * 128;
    const int fb0 = ftile * 128;

    const int tid  = threadIdx.x;
    const int lane = tid & 63;
    const int wave = tid >> 6;          // 0..3
    const int l15  = lane & 15;
    const int g4   = lane >> 4;         // 0..3
    const int wm   = wave >> 1;         // 0..1
    const int wn   = wave & 1;          // 0..1
    const int colr = ((g4 ^ ((l15 >> 1) & 3)) << 4);        // swizzled read chunk
    const int rdA = (wm * 64 + l15) * 64 + colr;            // + ai*1024
    const int rdB = 8192 + (wn * 64 + l15) * 64 + colr;     // + bj*1024

    // ---- staging geometry: thread covers rows r0, r0+64, chunk tid&3 ----
    const int r0 = tid >> 2;                             // 0..63
    const int sw = ((tid & 3) ^ ((tid >> 3) & 3)) << 4;  // inverse-swizzled src col
    const int p0 = (int)m0 + r0;
    const int p1 = p0 + 64;
    const int rem0 = p0 % 3136;
    const int rem1 = p1 % 3136;
    const int y0 = rem0 / 56, x0 = rem0 - (rem0 / 56) * 56;
    const int y1 = rem1 / 56, x1 = rem1 - (rem1 / 56) * 56;

    auto stage = [&](int kt, int sbuf) {
        int cc = (kt * 57) >> 9;             // kt/9 for kt<81
        int s  = kt - 9 * cc;
        int s3 = (s * 171) >> 9;             // s/3
        int dy = s3 - 1;
        int dx = s - 3 * s3 - 1;
        int doff = dy * 56 + dx;
        size_t cb = (size_t)(cc << 6) + sw;
        bool v0 = ((unsigned)(y0 + dy) < 56u) & ((unsigned)(x0 + dx) < 56u);
        bool v1 = ((unsigned)(y1 + dy) < 56u) & ((unsigned)(x1 + dx) < 56u);
        const char* a0 = v0 ? xbp + (size_t)(p0 + doff) * 512 + cb : zp + sw;
        const char* a1 = v1 ? xbp + (size_t)(p1 + doff) * 512 + cb : zp + sw;
        const char* b0 = wbp + (size_t)((s << 8) + fb0 + r0) * 512 + cb;
        const char* b1 = b0 + (size_t)64 * 512;
        char* L = &sm[sbuf][0];
        GLOAD_LDS16(a0, L + tid * 16);
        GLOAD_LDS16(a1, L + 4096 + tid * 16);
        GLOAD_LDS16(b0, L + 8192 + tid * 16);
        GLOAD_LDS16(b1, L + 12288 + tid * 16);
    };

    f32x4 acc[4][4];
#pragma unroll
    for (int i = 0; i < 4; ++i)
#pragma unroll
        for (int j = 0; j < 4; ++j)
            acc[i][j] = (f32x4){0.f, 0.f, 0.f, 0.f};

#define STEP(T, BUF, SBUF, DOSTAGE, WAITN)                                   \
    {                                                                        \
        asm volatile("s_waitcnt vmcnt(" WAITN ")" ::: "memory");             \
        __builtin_amdgcn_s_barrier();                                        \
        asm volatile("" ::: "memory");                                       \
        const char* Lb = &sm[(BUF)][0];                                      \
        bf16x8 Afr[4], Bfr[4];                                               \
        _Pragma("unroll")                                                    \
        for (int ai = 0; ai < 4; ++ai)                                       \
            Afr[ai] = *reinterpret_cast<const bf16x8*>(Lb + rdA + ai * 1024);\
        _Pragma("unroll")                                                    \
        for (int bj = 0; bj < 4; ++bj)                                       \
            Bfr[bj] = *reinterpret_cast<const bf16x8*>(Lb + rdB + bj * 1024);\
        if (DOSTAGE) stage((T) + 2, (SBUF));                                 \
        _Pragma("unroll")                                                    \
        for (int ai = 0; ai < 4; ++ai)                                       \
            _Pragma("unroll")                                                \
            for (int bj = 0; bj < 4; ++bj)                                   \
                acc[ai][bj] = __builtin_amdgcn_mfma_f32_16x16x32_bf16(       \
                    Afr[ai], Bfr[bj], acc[ai][bj], 0, 0, 0);                 \
    }

    // ---- prologue: 2 steps in flight ----
    stage(0, 0);
    stage(1, 1);

    // ---- main loop: t = 0..68 in triples (buf = t%3, stage buf = (t+2)%3) ----
    for (int t = 0; t < 69; t += 3) {
        STEP(t,     0, 2, true, "4");
        STEP(t + 1, 1, 0, true, "4");
        STEP(t + 2, 2, 1, true, "4");
    }
    // ---- tail: 69 (stages 71), 70, 71 ----
    STEP(69, 0, 2, true,  "4");
    STEP(70, 1, 0, false, "4");
    STEP(71, 2, 1, false, "0");

#undef STEP

    // ---- epilogue: D col(f)=lane&15, row(pixel)=(lane>>4)*4+j ----
#pragma unroll
    for (int ai = 0; ai < 4; ++ai) {
#pragma unroll
        for (int j = 0; j < 4; ++j) {
            long row = m0 + wm * 64 + ai * 16 + g4 * 4 + j;
            float* op = out + row * C_F + fb0 + wn * 64 + l15;
#pragma unroll
            for (int bj = 0; bj < 4; ++bj)
                op[bj * 16] = acc[ai][bj][j];
        }
    }
}

// ---- fallback (small ws): direct-from-global version ----
__global__ __launch_bounds__(256) void conv_fallback_kernel(
    const float* __restrict__ xf,
    const __bf16* __restrict__ wbT, const char* __restrict__ zbuf,
    float* __restrict__ out) {

    const int lane = threadIdx.x & 63;
    const int wave = threadIdx.x >> 6;
    const int l15  = lane & 15;
    const int g    = lane >> 4;
    const int goff = g * 8;
    const long m0  = (long)blockIdx.x * 64;
    const int fbase = wave * 64;

    int ry[4], rx[4];
    long rbase[4];
#pragma unroll
    for (int ai = 0; ai < 4; ++ai) {
        int rr = (int)m0 + ai * 16 + l15;
        int b = rr / 3136;
        int rem = rr - b * 3136;
        int yy2 = rem / 56;
        ry[ai] = yy2;
        rx[ai] = rem - yy2 * 56;
        rbase[ai] = (long)rr * C_C;
    }

    f32x4 acc[4][4];
#pragma unroll
    for (int i = 0; i < 4; ++i)
#pragma unroll
        for (int j = 0; j < 4; ++j)
            acc[i][j] = (f32x4){0.f, 0.f, 0.f, 0.f};

    for (int s = 0; s < 9; ++s) {
        const int dy = s / 3 - 1;
        const int dx = (s - (s / 3) * 3) - 1;
        const float* af[4];
#pragma unroll
        for (int ai = 0; ai < 4; ++ai) {
            bool v = ((unsigned)(ry[ai] + dy) < 56u) & ((unsigned)(rx[ai] + dx) < 56u);
            long off = rbase[ai] + (long)(dy * C_W + dx) * C_C + goff;
            af[ai] = v ? (xf + off) : ((const float*)zbuf + goff);
        }
        const __bf16* bp = wbT + ((size_t)(s * 256 + fbase + l15)) * C_C + goff;

#pragma unroll
        for (int cc = 0; cc < 8; ++cc) {
            const int c0 = cc * 32;
            bf16x8 A[4], Bf[4];
#pragma unroll
            for (int ai = 0; ai < 4; ++ai) {
                const f32x4* p = reinterpret_cast<const f32x4*>(af[ai] + c0);
                f32x4 u = p[0], w2 = p[1];
                bf16x8 t;
                t[0] = (__bf16)u[0]; t[1] = (__bf16)u[1]; t[2] = (__bf16)u[2]; t[3] = (__bf16)u[3];
                t[4] = (__bf16)w2[0]; t[5] = (__bf16)w2[1]; t[6] = (__bf16)w2[2]; t[7] = (__bf16)w2[3];
                A[ai] = t;
            }
#pragma unroll
            for (int bj = 0; bj < 4; ++bj)
                Bf[bj] = *reinterpret_cast<const bf16x8*>(bp + bj * 16 * C_C + c0);
#pragma unroll
            for (int ai = 0; ai < 4; ++ai)
#pragma unroll
                for (int bj = 0; bj < 4; ++bj)
                    acc[ai][bj] = __builtin_amdgcn_mfma_f32_16x16x32_bf16(A[ai], Bf[bj], acc[ai][bj], 0, 0, 0);
        }
    }

#pragma unroll
    for (int ai = 0; ai < 4; ++ai) {
#pragma unroll
        for (int j = 0; j < 4; ++j) {
            long row = m0 + ai * 16 + g * 4 + j;
            float* op = out + row * C_F + fbase + l15;
#pragma unroll
            for (int bj = 0; bj < 4; ++bj)
                op[bj * 16] = acc[ai][bj][j];
        }
    }
}

extern "C" void kernel_launch(void* const* d_in, const int* in_sizes, int n_in,
                              void* d_out, int out_size, void* d_ws, size_t ws_size,
                              hipStream_t stream) {
    const float* x = (const float*)d_in[0];
    const float* w = (const float*)d_in[1];
    float* out = (float*)d_out;

    char* ws = (char*)d_ws;
    __bf16* wbT = (__bf16*)ws;
    char* zbuf = ws + WB_BYTES;
    __bf16* xb = (__bf16*)(ws + XB_OFF);

    const bool prex = ws_size >= (size_t)XB_OFF + (size_t)X_ELEMS * 2;

    prep_w_kernel<<<WB_ELEMS / 256, 256, 0, stream>>>(w, wbT);
    zero_kernel<<<1, 256, 0, stream>>>((float*)zbuf);

    if (prex) {
        prep_x_kernel<<<X_ELEMS / 8 / 256, 256, 0, stream>>>(x, xb);
        conv_p3_kernel<<<N_PIX / 128 * 2, 256, 0, stream>>>(
            (const char*)xb, (const char*)wbT, zbuf, out);
    } else {
        conv_fallback_kernel<<<N_PIX / 64, 256, 0, stream>>>(x, wbT, zbuf, out);
    }
}

// Round 8
// 316.212 us; speedup vs baseline: 1.0775x; 1.0023x over previous
//
#include <hip/hip_runtime.h>
#include <hip/hip_bf16.h>
#include <hip/hip_fp16.h>

typedef __bf16 bf16x8 __attribute__((ext_vector_type(8)));
typedef float  f32x4  __attribute__((ext_vector_type(4)));
typedef float  f32x16 __attribute__((ext_vector_type(16)));

#define C_H 56
#define C_W 56
#define C_C 256
#define C_F 256
#define C_B 64
#define N_PIX (C_B * C_H * C_W)          // 200704
#define WB_ELEMS (9 * C_C * C_F)         // 589824
#define WB_BYTES (WB_ELEMS * 2)          // 1179648
#define XQ_OFF WB_BYTES                  // padded-x right after weights
#define XQ_PIX (C_B * 58 * 58)           // 215296 padded pixels
#define XQ_BYTES ((size_t)XQ_PIX * 512)  // 110,231,552
#define X_ELEMS (N_PIX * C_C)            // 51380224

#define GLOAD_LDS16(g, l)                                                   \
    __builtin_amdgcn_global_load_lds(                                        \
        (const __attribute__((address_space(1))) void*)(g),                  \
        (__attribute__((address_space(3))) void*)(l), 16, 0, 0)

// ---- prep: binarize weights into direct-load fragment layout ----
// w[s][c][f] fp32 -> wq[s][cc][kk][half][f][8j] bf16  (c = cc*32+kk*16+half*8+j)
__global__ void prep_w2_kernel(const float* __restrict__ w, __bf16* __restrict__ wq) {
    int idx = blockIdx.x * 256 + threadIdx.x;       // 589824
    int f = idx & 255;
    int c = (idx >> 8) & 255;
    int s = idx >> 16;
    float wf = w[idx];
    float v = __half2float(__float2half(wf));       // fp16 round-trip
    float sgn = (v > 0.f) ? 1.f : ((v < 0.f) ? -1.f : 0.f);
    int cc = c >> 5, r5 = c & 31;
    int kk = r5 >> 4, half = (r5 >> 3) & 1, j = r5 & 7;
    int off = (((s * 8 + cc) * 2 + kk) * 2 + half) * 2048 + f * 8 + j;
    wq[off] = (__bf16)sgn;
}

// ---- prep: zero the pad ring of xq ----
__global__ void border_zero_kernel(float* __restrict__ xq) {
    int idx = blockIdx.x * 256 + threadIdx.x;       // 466944 total f32x4 writes
    int q = idx & 31;                                // 32 x 16B = 512B per pixel
    int pe = idx >> 5;                               // 0..14591
    int b = pe / 228;
    int e = pe - b * 228;
    int y, x;
    if (e < 58)       { y = 0;       x = e; }
    else if (e < 116) { y = 57;      x = e - 58; }
    else if (e < 172) { y = e - 115; x = 0; }
    else              { y = e - 171; x = 57; }
    f32x4* p = reinterpret_cast<f32x4*>(xq) + ((size_t)(b * 3364 + y * 58 + x) * 32 + q);
    *p = (f32x4){0.f, 0.f, 0.f, 0.f};
}

// ---- prep: x fp32 -> bf16 into padded [b][58][58][256] layout ----
__global__ void prep_x_pad_kernel(const float* __restrict__ x, __bf16* __restrict__ xq) {
    int i = blockIdx.x * 256 + threadIdx.x;          // X_ELEMS/8 threads
    int px = i >> 5;                                 // interior pixel
    int c8 = i & 31;
    int b = px / 3136;
    int rem = px - b * 3136;
    int y = rem / 56;
    int x2 = rem - y * 56;
    const f32x4* p = reinterpret_cast<const f32x4*>(x) + (size_t)i * 2;
    f32x4 a = p[0], bb = p[1];
    bf16x8 o;
    o[0] = (__bf16)a[0];  o[1] = (__bf16)a[1];  o[2] = (__bf16)a[2];  o[3] = (__bf16)a[3];
    o[4] = (__bf16)bb[0]; o[5] = (__bf16)bb[1]; o[6] = (__bf16)bb[2]; o[7] = (__bf16)bb[3];
    size_t dst = (size_t)(b * 3364 + (y + 1) * 58 + (x2 + 1)) * 32 + c8;
    reinterpret_cast<bf16x8*>(xq)[dst] = o;
}

// padded-space shift offset for tap s, in bytes
#define DOFFB(S) ((((S) / 3 - 1) * 58 + ((S) % 3 - 1)) * 512)

// ---- main conv: 256x128 tile, 4 waves (2Mx2N, 128x64/wave), 32x32x16 MFMA ----
// A: LDS-staged (3 bufs x 16KB, lookahead +2, counted vmcnt(4), 1 barrier/step)
// B: direct-from-L2 register prefetch (1 step ahead), fragment-major layout.
// K order: kt = cc*9 + s (s fastest). Swizzle on A: chunk ^= (row>>1)&3.
__global__ __launch_bounds__(256, 2) void conv_k32_kernel(
    const char* __restrict__ xq,       // padded bf16 x, 512B rows
    const char* __restrict__ wqp,      // fragment-major bf16 weights
    float* __restrict__ out) {

    __shared__ __align__(16) char sm[3][16384];

    // XCD-chunked bijective swizzle: 1568 = 8 * 196
    const int nbid = (blockIdx.x & 7) * 196 + (blockIdx.x >> 3);
    const int mtile = nbid >> 1;
    const int ftile = nbid & 1;
    const long m0 = (long)mtile * 256;
    const int fb = ftile * 128;

    const int tid  = threadIdx.x;
    const int lane = tid & 63;
    const int w    = tid >> 6;          // 0..3
    const int l31  = lane & 31;
    const int half = lane >> 5;         // 0..1
    const int wm   = w >> 1;            // 0..1 (M half: 128 rows)
    const int wn   = w & 1;             // 0..1 (N half: 64 cols)

    // A fragment read addressing (swizzled)
    const int x31 = (l31 >> 1) & 3;
    const int colA0 = ((half ^ x31) << 4);
    const int colA1 = colA0 ^ 32;
    const int rdAbase = (wm * 128 + l31) * 64;

    // B direct-load per-lane base  (FIX R7->R8: + wn*64 f-offset)
    const int BL = (fb + wn * 64 + l31) * 16 + half * 4096;

    // A staging: source swizzle + padded pixel offsets for 4 rows
    const int sw = ((lane & 3) ^ ((lane >> 3) & 3)) << 4;
    int P[4];
    int ldst[4];
#pragma unroll
    for (int i = 0; i < 4; ++i) {
        int r = ((i * 4 + w) << 4) + (lane >> 2);    // 0..255
        int p = (int)m0 + r;
        int b = p / 3136;
        int rem = p - b * 3136;
        int y = rem / 56;
        int xx = rem - y * 56;
        P[i] = (b * 3364 + (y + 1) * 58 + (xx + 1)) * 512 + sw;
        ldst[i] = (i * 4 + w) * 1024 + lane * 16;
    }

    f32x16 acc[4][2];
#pragma unroll
    for (int i = 0; i < 4; ++i)
#pragma unroll
        for (int j = 0; j < 2; ++j)
            acc[i][j] = (f32x16)(0.f);

    bf16x8 Bp0[2][2], Bp1[2][2];

#define ASTAGE(S2, SB2, CA2)                                                 \
    {                                                                        \
        _Pragma("unroll")                                                    \
        for (int i = 0; i < 4; ++i)                                          \
            GLOAD_LDS16(xq + (P[i] + DOFFB(S2) + (CA2)),                     \
                        &sm[(SB2)][0] + ldst[i]);                            \
    }

#define BPREF(DST, S1, CB1)                                                  \
    {                                                                        \
        _Pragma("unroll")                                                    \
        for (int nt = 0; nt < 2; ++nt)                                       \
            _Pragma("unroll")                                                \
            for (int kk = 0; kk < 2; ++kk)                                   \
                DST[nt][kk] = *reinterpret_cast<const bf16x8*>(              \
                    wqp + (BL + nt * 512 + (S1) * 131072 + kk * 8192 + (CB1)));\
    }

#define STEP(BUF, CONS, LOAD, S1, CB1, S2, SB2, CA2, DOSTAGE, WVM)           \
    {                                                                        \
        asm volatile("s_waitcnt vmcnt(" WVM ")" ::: "memory");               \
        __builtin_amdgcn_s_barrier();                                        \
        const char* Lb = &sm[(BUF)][0];                                      \
        bf16x8 Af[4][2];                                                     \
        _Pragma("unroll")                                                    \
        for (int mt = 0; mt < 4; ++mt) {                                     \
            Af[mt][0] = *reinterpret_cast<const bf16x8*>(Lb + rdAbase + mt * 2048 + colA0); \
            Af[mt][1] = *reinterpret_cast<const bf16x8*>(Lb + rdAbase + mt * 2048 + colA1); \
        }                                                                    \
        BPREF(LOAD, S1, CB1);                                                \
        if (DOSTAGE) ASTAGE(S2, SB2, CA2);                                   \
        _Pragma("unroll")                                                    \
        for (int mt = 0; mt < 4; ++mt)                                       \
            _Pragma("unroll")                                                \
            for (int nt = 0; nt < 2; ++nt)                                   \
                _Pragma("unroll")                                            \
                for (int kk = 0; kk < 2; ++kk)                               \
                    acc[mt][nt] = __builtin_amdgcn_mfma_f32_32x32x16_bf16(   \
                        Af[mt][kk], CONS[nt][kk], acc[mt][nt], 0, 0, 0);     \
    }

// 9 steps of one cc; PA/PB are consume/load role arrays for even S
#define NINE(CA, CB, PA, PB, DS7, DS8, WV8)                                  \
    STEP(0, PA, PB, 1, (CB),         2, 2, (CA),      true,  "4")            \
    STEP(1, PB, PA, 2, (CB),         3, 0, (CA),      true,  "4")            \
    STEP(2, PA, PB, 3, (CB),         4, 1, (CA),      true,  "4")            \
    STEP(0, PB, PA, 4, (CB),         5, 2, (CA),      true,  "4")            \
    STEP(1, PA, PB, 5, (CB),         6, 0, (CA),      true,  "4")            \
    STEP(2, PB, PA, 6, (CB),         7, 1, (CA),      true,  "4")            \
    STEP(0, PA, PB, 7, (CB),         8, 2, (CA),      true,  "4")            \
    STEP(1, PB, PA, 8, (CB),         0, 0, (CA) + 64, DS7,   "4")            \
    STEP(2, PA, PB, 0, (CB) + 16384, 1, 1, (CA) + 64, DS8,   WV8)

    // ---- prologue: A(0)->buf0, A(1)->buf1, B(0)->Bp0 ----
    ASTAGE(0, 0, 0);
    { // stage(1): s=1, cc=0 -> buf1
        _Pragma("unroll")
        for (int i = 0; i < 4; ++i)
            GLOAD_LDS16(xq + (P[i] + DOFFB(1)), &sm[1][0] + ldst[i]);
    }
    BPREF(Bp0, 0, 0);
    asm volatile("s_waitcnt vmcnt(0)" ::: "memory");
    __builtin_amdgcn_s_barrier();

    // ---- main: ccp = 0..2 (cc pairs 0-5), all staging on ----
    for (int ccp = 0; ccp < 3; ++ccp) {
        const int a0 = ccp * 128;           // cc*64 for even cc
        const int b0 = ccp * 32768;         // cc*16384 for even cc
        NINE(a0,      b0,         Bp0, Bp1, true, true, "4")
        NINE(a0 + 64, b0 + 16384, Bp1, Bp0, true, true, "4")
    }
    // ---- peeled ccp=3 (cc 6,7): last two steps don't stage; last waits 0 ----
    {
        const int a0 = 384;                 // 3*128
        const int b0 = 98304;               // 3*32768
        NINE(a0,      b0,         Bp0, Bp1, true,  true,  "4")
        NINE(a0 + 64, b0 + 16384, Bp1, Bp0, false, false, "0")
    }

#undef NINE
#undef STEP
#undef BPREF
#undef ASTAGE

    // ---- epilogue: D col(f)=lane&31, row=(j&3)+8*(j>>2)+4*half ----
#pragma unroll
    for (int mt = 0; mt < 4; ++mt) {
#pragma unroll
        for (int nt = 0; nt < 2; ++nt) {
#pragma unroll
            for (int j = 0; j < 16; ++j) {
                long row = m0 + wm * 128 + mt * 32 + (j & 3) + 8 * (j >> 2) + 4 * half;
                int col = fb + wn * 64 + nt * 32 + l31;
                out[row * C_F + col] = acc[mt][nt][j];
            }
        }
    }
}

// ---- fallback path (small ws): direct-from-global, fp32 loads ----
__global__ void prep_w_kernel(const float* __restrict__ w, __bf16* __restrict__ wbT) {
    int idx = blockIdx.x * 256 + threadIdx.x;
    int f = idx & 255;
    int c = (idx >> 8) & 255;
    int s = idx >> 16;
    float wf = w[idx];
    float v = __half2float(__float2half(wf));
    float sgn = (v > 0.f) ? 1.f : ((v < 0.f) ? -1.f : 0.f);
    wbT[(s << 16) + (f << 8) + c] = (__bf16)sgn;
}

__global__ void zero_kernel(float* __restrict__ z) {
    z[threadIdx.x] = 0.f;
}

__global__ __launch_bounds__(256) void conv_fallback_kernel(
    const float* __restrict__ xf,
    const __bf16* __restrict__ wbT, const char* __restrict__ zbuf,
    float* __restrict__ out) {

    const int lane = threadIdx.x & 63;
    const int wave = threadIdx.x >> 6;
    const int l15  = lane & 15;
    const int g    = lane >> 4;
    const int goff = g * 8;
    const long m0  = (long)blockIdx.x * 64;
    const int fbase = wave * 64;

    int ry[4], rx[4];
    long rbase[4];
#pragma unroll
    for (int ai = 0; ai < 4; ++ai) {
        int rr = (int)m0 + ai * 16 + l15;
        int b = rr / 3136;
        int rem = rr - b * 3136;
        int yy2 = rem / 56;
        ry[ai] = yy2;
        rx[ai] = rem - yy2 * 56;
        rbase[ai] = (long)rr * C_C;
    }

    f32x4 acc[4][4];
#pragma unroll
    for (int i = 0; i < 4; ++i)
#pragma unroll
        for (int j = 0; j < 4; ++j)
            acc[i][j] = (f32x4){0.f, 0.f, 0.f, 0.f};

    for (int s = 0; s < 9; ++s) {
        const int dy = s / 3 - 1;
        const int dx = (s - (s / 3) * 3) - 1;
        const float* af[4];
#pragma unroll
        for (int ai = 0; ai < 4; ++ai) {
            bool v = ((unsigned)(ry[ai] + dy) < 56u) & ((unsigned)(rx[ai] + dx) < 56u);
            long off = rbase[ai] + (long)(dy * C_W + dx) * C_C + goff;
            af[ai] = v ? (xf + off) : ((const float*)zbuf + goff);
        }
        const __bf16* bp = wbT + ((size_t)(s * 256 + fbase + l15)) * C_C + goff;

#pragma unroll
        for (int cc = 0; cc < 8; ++cc) {
            const int c0 = cc * 32;
            bf16x8 A[4], Bf[4];
#pragma unroll
            for (int ai = 0; ai < 4; ++ai) {
                const f32x4* p = reinterpret_cast<const f32x4*>(af[ai] + c0);
                f32x4 u = p[0], w2 = p[1];
                bf16x8 t;
                t[0] = (__bf16)u[0]; t[1] = (__bf16)u[1]; t[2] = (__bf16)u[2]; t[3] = (__bf16)u[3];
                t[4] = (__bf16)w2[0]; t[5] = (__bf16)w2[1]; t[6] = (__bf16)w2[2]; t[7] = (__bf16)w2[3];
                A[ai] = t;
            }
#pragma unroll
            for (int bj = 0; bj < 4; ++bj)
                Bf[bj] = *reinterpret_cast<const bf16x8*>(bp + bj * 16 * C_C + c0);
#pragma unroll
            for (int ai = 0; ai < 4; ++ai)
#pragma unroll
                for (int bj = 0; bj < 4; ++bj)
                    acc[ai][bj] = __builtin_amdgcn_mfma_f32_16x16x32_bf16(A[ai], Bf[bj], acc[ai][bj], 0, 0, 0);
        }
    }

#pragma unroll
    for (int ai = 0; ai < 4; ++ai) {
#pragma unroll
        for (int j = 0; j < 4; ++j) {
            long row = m0 + ai * 16 + g * 4 + j;
            float* op = out + row * C_F + fbase + l15;
#pragma unroll
            for (int bj = 0; bj < 4; ++bj)
                op[bj * 16] = acc[ai][bj][j];
        }
    }
}

extern "C" void kernel_launch(void* const* d_in, const int* in_sizes, int n_in,
                              void* d_out, int out_size, void* d_ws, size_t ws_size,
                              hipStream_t stream) {
    const float* x = (const float*)d_in[0];
    const float* w = (const float*)d_in[1];
    float* out = (float*)d_out;

    char* ws = (char*)d_ws;
    const bool big = ws_size >= (size_t)XQ_OFF + XQ_BYTES;

    if (big) {
        __bf16* wq = (__bf16*)ws;
        __bf16* xq = (__bf16*)(ws + XQ_OFF);
        prep_w2_kernel<<<WB_ELEMS / 256, 256, 0, stream>>>(w, wq);
        border_zero_kernel<<<1824, 256, 0, stream>>>((float*)xq);
        prep_x_pad_kernel<<<X_ELEMS / 8 / 256, 256, 0, stream>>>(x, xq);
        conv_k32_kernel<<<N_PIX / 256 * 2, 256, 0, stream>>>(
            (const char*)xq, (const char*)wq, out);
    } else {
        __bf16* wbT = (__bf16*)ws;
        char* zbuf = ws + WB_BYTES;
        prep_w_kernel<<<WB_ELEMS / 256, 256, 0, stream>>>(w, wbT);
        zero_kernel<<<1, 256, 0, stream>>>((float*)zbuf);
        conv_fallback_kernel<<<N_PIX / 64, 256, 0, stream>>>(x, wbT, zbuf, out);
    }
}